// Round 1
// baseline (11632.602 us; speedup 1.0000x reference)
//
#include <hip/hip_runtime.h>

// VQ-VAE quantization: N=32768 tokens, K=4096 codes, D=256, fp32.
// Outputs (concatenated as float32 in d_out):
//   z_q     [N*D]  = embed[idx[i]]
//   idx     [N]    = argmin_k ||z_e[i] - embed[k]||^2   (written as float)
//   one_hot [N*K]
//
// argmin(d) with d = ||z||^2 - 2 z.e + ||e||^2 : ||z||^2 is row-constant ->
// rank by (||e||^2 - 2 z.e) only. ||e||^2 accumulated on the fly from the
// staged embed tiles (no separate kernel, no workspace).
//
// Block: 256 threads (16x16), tile 64 rows x 128 codes, D chunked by 64.
// Per-thread 4x8 register blocking: 128 FMA per 12 ds_read_b128 -> VALU-bound.
// fp32 vector floor = 68.7 GFLOP / 157.3 TF = 437 us.

#define N_TOK 32768
#define K_CODE 4096
#define D_DIM 256

#define TM 64        // rows per block
#define TK 128       // codes per k-iteration
#define TD 64        // d-chunk
#define PAD 68       // LDS row pitch in floats (64 + 4): stride%32==4 -> spread banks

__launch_bounds__(256, 2)
__global__ void vq_fused(const float* __restrict__ z_e,
                         const float* __restrict__ embed,
                         float* __restrict__ out) {
    __shared__ float zs[TM * PAD];        // 17408 B
    __shared__ float es[TK * PAD];        // 34816 B
    __shared__ float e2part[TK][2];       // 1024 B
    __shared__ float redv[TM][17];        // pad 17 breaks bank stride
    __shared__ int   redi[TM][17];
    __shared__ int   bk_lds[TM];

    const int t    = threadIdx.x;
    const int ty   = t >> 4;    // 0..15
    const int tx   = t & 15;    // 0..15
    const int w    = t >> 6;    // wave 0..3
    const int lane = t & 63;

    const int row0 = blockIdx.x * TM;

    // staging assignments
    const int zrow = t >> 2;    // 0..63, 4 threads/row, 16 floats each
    const int zseg = t & 3;
    const int erow = t >> 1;    // 0..127, 2 threads/row, 32 floats each
    const int eseg = t & 1;

    float best_val[4];
    int   best_idx[4];
#pragma unroll
    for (int r = 0; r < 4; ++r) { best_val[r] = 3.0e38f; best_idx[r] = 0; }

    for (int kc = 0; kc < K_CODE; kc += TK) {
        float acc[4][8];
#pragma unroll
        for (int r = 0; r < 4; ++r)
#pragma unroll
            for (int c = 0; c < 8; ++c) acc[r][c] = 0.0f;

        for (int dc = 0; dc < D_DIM; dc += TD) {
            __syncthreads();   // protect LDS tiles from previous readers
            if (dc == 0) e2part[erow][eseg] = 0.0f;  // own slot; same thread accumulates

            // stage z tile: 64 x 64 floats
            {
                const float* src = z_e + (size_t)(row0 + zrow) * D_DIM + dc + zseg * 16;
                float* dst = &zs[zrow * PAD + zseg * 16];
#pragma unroll
                for (int j = 0; j < 4; ++j) {
                    float4 v = *(const float4*)(src + j * 4);
                    *(float4*)(dst + j * 4) = v;
                }
            }
            // stage e tile: 128 x 64 floats, accumulate ||e||^2 partials
            {
                const float* src = embed + (size_t)(kc + erow) * D_DIM + dc + eseg * 32;
                float* dst = &es[erow * PAD + eseg * 32];
                float s = 0.0f;
#pragma unroll
                for (int j = 0; j < 8; ++j) {
                    float4 v = *(const float4*)(src + j * 4);
                    *(float4*)(dst + j * 4) = v;
                    s += v.x * v.x + v.y * v.y + v.z * v.z + v.w * v.w;
                }
                e2part[erow][eseg] += s;
            }
            __syncthreads();

            // compute: rows r*16+ty (addr varies with ty only -> 4 addrs/wave,
            // 16-lane broadcast, conflict-free); cols c*16+tx (16 addrs/wave,
            // stride 68 words -> 2-way alias = free)
#pragma unroll
            for (int g = 0; g < 16; ++g) {
                float4 za[4];
#pragma unroll
                for (int r = 0; r < 4; ++r)
                    za[r] = *(const float4*)&zs[(r * 16 + ty) * PAD + g * 4];
                float4 ea[8];
#pragma unroll
                for (int c = 0; c < 8; ++c)
                    ea[c] = *(const float4*)&es[(c * 16 + tx) * PAD + g * 4];
#pragma unroll
                for (int r = 0; r < 4; ++r)
#pragma unroll
                    for (int c = 0; c < 8; ++c)
                        acc[r][c] += za[r].x * ea[c].x + za[r].y * ea[c].y
                                   + za[r].z * ea[c].z + za[r].w * ea[c].w;
            }
        }

        // merge: val = ||e||^2 - 2 z.e ; strict < keeps first occurrence
        // (k strictly increases across c and kc for a fixed thread)
#pragma unroll
        for (int c = 0; c < 8; ++c) {
            const int kl = c * 16 + tx;
            const float e2v = e2part[kl][0] + e2part[kl][1];
            const int kg = kc + kl;
#pragma unroll
            for (int r = 0; r < 4; ++r) {
                const float val = e2v - 2.0f * acc[r][c];
                if (val < best_val[r]) { best_val[r] = val; best_idx[r] = kg; }
            }
        }
    }

    // cross-thread (tx) reduction per row; tie -> smaller index (numpy argmin)
    __syncthreads();
#pragma unroll
    for (int r = 0; r < 4; ++r) {
        const int row = r * 16 + ty;
        redv[row][tx] = best_val[r];
        redi[row][tx] = best_idx[r];
    }
    __syncthreads();
    if (t < TM) {
        float bv = redv[t][0];
        int   bi = redi[t][0];
#pragma unroll
        for (int j = 1; j < 16; ++j) {
            const float v = redv[t][j];
            const int   i2 = redi[t][j];
            if (v < bv || (v == bv && i2 < bi)) { bv = v; bi = i2; }
        }
        bk_lds[t] = bi;
        out[(size_t)N_TOK * D_DIM + (size_t)(row0 + t)] = (float)bi;  // idx as float
    }
    __syncthreads();

    float* zq = out;                                              // [N, D]
    float* oh = out + (size_t)N_TOK * D_DIM + N_TOK;              // [N, K]

    // z_q gather: one row per wave-iteration, 64 lanes x float4 = 256 floats
#pragma unroll
    for (int rr = 0; rr < 16; ++rr) {
        const int row = rr * 4 + w;
        const int bk = bk_lds[row];
        const float4 v = *(const float4*)&embed[(size_t)bk * D_DIM + lane * 4];
        *(float4*)&zq[(size_t)(row0 + row) * D_DIM + lane * 4] = v;
    }

    // one_hot: one row per wave-iteration, 1KB coalesced stores
#pragma unroll 1
    for (int rr = 0; rr < 16; ++rr) {
        const int row = rr * 4 + w;
        const int bk = bk_lds[row];
        float* ohrow = &oh[(size_t)(row0 + row) * K_CODE];
#pragma unroll
        for (int g = 0; g < 16; ++g) {
            const int base = (g * 64 + lane) * 4;
            float4 v;
            v.x = (bk == base    ) ? 1.0f : 0.0f;
            v.y = (bk == base + 1) ? 1.0f : 0.0f;
            v.z = (bk == base + 2) ? 1.0f : 0.0f;
            v.w = (bk == base + 3) ? 1.0f : 0.0f;
            *(float4*)&ohrow[base] = v;
        }
    }
}

extern "C" void kernel_launch(void* const* d_in, const int* in_sizes, int n_in,
                              void* d_out, int out_size, void* d_ws, size_t ws_size,
                              hipStream_t stream) {
    const float* z_e   = (const float*)d_in[0];
    const float* embed = (const float*)d_in[1];
    float* out = (float*)d_out;
    // 512 blocks = 2 per CU exactly; 64 rows per block
    hipLaunchKernelGGL(vq_fused, dim3(N_TOK / TM), dim3(256), 0, stream,
                       z_e, embed, out);
}

// Round 3
// 9185.719 us; speedup vs baseline: 1.2664x; 1.2664x over previous
//
#include <hip/hip_runtime.h>

// VQ-VAE quantization: N=32768 tokens, K=4096 codes, D=256, fp32.
// Outputs (concatenated float32 in d_out): z_q [N*D], idx [N] (as float), one_hot [N*K].
//
// Split-kernel structure:
//  1) vq_argmin: compute-only, read-mostly (embed 4MB -> L2-resident, z_e 32MB -> L3).
//     Writes only idx (128 KB). Rank by (||e||^2 - 2 z.e); ||z||^2 drops out of argmin.
//  2) vq_epilogue: pure streaming writes (z_q 32MB + one_hot 512MB) with nontemporal
//     stores, reading idx back from d_out (float holds ints < 2^24 exactly).
// Rationale: round-1 fused the 570MB write stream into the compute kernel; it thrashed
// L2/L3 (FETCH+WRITE 37GB vs 0.58GB floor), making every staging re-read an unhidden
// HBM miss (VALUBusy 9%).

#define N_TOK 32768
#define K_CODE 4096
#define D_DIM 256

#define TM 64        // rows per block
#define TK 128       // codes per k-iteration
#define TD 64        // d-chunk
#define PAD 68       // LDS row pitch (64+4 floats): breaks power-of-2 bank stride

// native clang vector type: __builtin_nontemporal_store rejects HIP's float4 class
typedef float f32x4 __attribute__((ext_vector_type(4)));

__launch_bounds__(256, 2)
__global__ void vq_argmin(const float* __restrict__ z_e,
                          const float* __restrict__ embed,
                          float* __restrict__ out) {
    __shared__ float zs[TM * PAD];        // 17408 B
    __shared__ float es[TK * PAD];        // 34816 B
    __shared__ float e2part[TK][2];       // 1024 B
    __shared__ float redv[TM][17];
    __shared__ int   redi[TM][17];

    const int t    = threadIdx.x;
    const int ty   = t >> 4;    // 0..15
    const int tx   = t & 15;    // 0..15
    const int row0 = blockIdx.x * TM;

    const int zrow = t >> 2;    // 0..63, 4 threads/row, 16 floats each
    const int zseg = t & 3;
    const int erow = t >> 1;    // 0..127, 2 threads/row, 32 floats each
    const int eseg = t & 1;

    float best_val[4];
    int   best_idx[4];
#pragma unroll
    for (int r = 0; r < 4; ++r) { best_val[r] = 3.0e38f; best_idx[r] = 0; }

    for (int kc = 0; kc < K_CODE; kc += TK) {
        float acc[4][8];
#pragma unroll
        for (int r = 0; r < 4; ++r)
#pragma unroll
            for (int c = 0; c < 8; ++c) acc[r][c] = 0.0f;

        for (int dc = 0; dc < D_DIM; dc += TD) {
            __syncthreads();   // protect LDS tiles from previous readers
            if (dc == 0) e2part[erow][eseg] = 0.0f;

            // stage z tile: 64 x 64 floats
            {
                const float* src = z_e + (size_t)(row0 + zrow) * D_DIM + dc + zseg * 16;
                float* dst = &zs[zrow * PAD + zseg * 16];
#pragma unroll
                for (int j = 0; j < 4; ++j)
                    *(float4*)(dst + j * 4) = *(const float4*)(src + j * 4);
            }
            // stage e tile: 128 x 64 floats, accumulate ||e||^2 partials
            {
                const float* src = embed + (size_t)(kc + erow) * D_DIM + dc + eseg * 32;
                float* dst = &es[erow * PAD + eseg * 32];
                float s = 0.0f;
#pragma unroll
                for (int j = 0; j < 8; ++j) {
                    float4 v = *(const float4*)(src + j * 4);
                    *(float4*)(dst + j * 4) = v;
                    s += v.x * v.x + v.y * v.y + v.z * v.z + v.w * v.w;
                }
                e2part[erow][eseg] += s;
            }
            __syncthreads();

            // 4x8 register tile: za addr varies with ty only (16-lane broadcast);
            // ea stride 68 words -> 2-way alias = free (m136)
#pragma unroll
            for (int g = 0; g < 16; ++g) {
                float4 za[4];
#pragma unroll
                for (int r = 0; r < 4; ++r)
                    za[r] = *(const float4*)&zs[(r * 16 + ty) * PAD + g * 4];
                float4 ea[8];
#pragma unroll
                for (int c = 0; c < 8; ++c)
                    ea[c] = *(const float4*)&es[(c * 16 + tx) * PAD + g * 4];
#pragma unroll
                for (int r = 0; r < 4; ++r)
#pragma unroll
                    for (int c = 0; c < 8; ++c)
                        acc[r][c] += za[r].x * ea[c].x + za[r].y * ea[c].y
                                   + za[r].z * ea[c].z + za[r].w * ea[c].w;
            }
        }

        // val = ||e||^2 - 2 z.e ; strict < keeps first occurrence
#pragma unroll
        for (int c = 0; c < 8; ++c) {
            const int kl = c * 16 + tx;
            const float e2v = e2part[kl][0] + e2part[kl][1];
            const int kg = kc + kl;
#pragma unroll
            for (int r = 0; r < 4; ++r) {
                const float val = e2v - 2.0f * acc[r][c];
                if (val < best_val[r]) { best_val[r] = val; best_idx[r] = kg; }
            }
        }
    }

    // cross-thread (tx) reduction per row; tie -> smaller index (numpy argmin)
    __syncthreads();
#pragma unroll
    for (int r = 0; r < 4; ++r) {
        const int row = r * 16 + ty;
        redv[row][tx] = best_val[r];
        redi[row][tx] = best_idx[r];
    }
    __syncthreads();
    if (t < TM) {
        float bv = redv[t][0];
        int   bi = redi[t][0];
#pragma unroll
        for (int j = 1; j < 16; ++j) {
            const float v = redv[t][j];
            const int   i2 = redi[t][j];
            if (v < bv || (v == bv && i2 < bi)) { bv = v; bi = i2; }
        }
        out[(size_t)N_TOK * D_DIM + (size_t)(row0 + t)] = (float)bi;  // idx as float
    }
}

// Epilogue: pure streaming writes. 32 rows/block, 4 waves -> 8 rows/wave.
__launch_bounds__(256, 2)
__global__ void vq_epilogue(const float* __restrict__ embed,
                            float* __restrict__ out) {
    const int t    = threadIdx.x;
    const int w    = t >> 6;
    const int lane = t & 63;
    const int row0 = blockIdx.x * 32;

    const float* idxf = out + (size_t)N_TOK * D_DIM;
    float* zq = out;
    float* oh = out + (size_t)N_TOK * D_DIM + N_TOK;

#pragma unroll 1
    for (int rr = 0; rr < 8; ++rr) {
        const int row = row0 + rr * 4 + w;
        const int bk = (int)idxf[row];

        // z_q row: 64 lanes x float4 = 256 floats (embed row is L2-hot)
        f32x4 v = *(const f32x4*)&embed[(size_t)bk * D_DIM + lane * 4];
        __builtin_nontemporal_store(v, (f32x4*)&zq[(size_t)row * D_DIM + lane * 4]);

        // one_hot row: 16 x 1KB coalesced nontemporal stores
        float* ohrow = &oh[(size_t)row * K_CODE];
#pragma unroll
        for (int g = 0; g < 16; ++g) {
            const int base = (g * 64 + lane) * 4;
            f32x4 u;
            u.x = (bk == base    ) ? 1.0f : 0.0f;
            u.y = (bk == base + 1) ? 1.0f : 0.0f;
            u.z = (bk == base + 2) ? 1.0f : 0.0f;
            u.w = (bk == base + 3) ? 1.0f : 0.0f;
            __builtin_nontemporal_store(u, (f32x4*)&ohrow[base]);
        }
    }
}

extern "C" void kernel_launch(void* const* d_in, const int* in_sizes, int n_in,
                              void* d_out, int out_size, void* d_ws, size_t ws_size,
                              hipStream_t stream) {
    const float* z_e   = (const float*)d_in[0];
    const float* embed = (const float*)d_in[1];
    float* out = (float*)d_out;

    hipLaunchKernelGGL(vq_argmin, dim3(N_TOK / TM), dim3(256), 0, stream,
                       z_e, embed, out);
    hipLaunchKernelGGL(vq_epilogue, dim3(N_TOK / 32), dim3(256), 0, stream,
                       embed, out);
}

// Round 4
// 1734.171 us; speedup vs baseline: 6.7079x; 5.2969x over previous
//
#include <hip/hip_runtime.h>

// VQ-VAE quantization: N=32768 tokens, K=4096 codes, D=256, fp32.
// Outputs (concatenated float32 in d_out): z_q [N*D], idx [N] (as float), one_hot [N*K].
//
// Round-4: kill the VGPR spill. Round-3 counters showed vq_argmin (logical writes:
// 128 KB) emitting 22.6 GB WRITE + 13.5 GB FETCH = scratch spill/fill, caused by the
// fully-unrolled 16x g-loop (192 ds_read_b128 + 2048 FMAs in one scheduling window)
// under the 128-VGPR cap. Fix: #pragma unroll 1 on the g-loop -> per-iter live set
// acc(32)+za(16)+ea(32)+addrs ~= 100 regs, fits the (256,2) cap with 2 blocks/CU.

#define N_TOK 32768
#define K_CODE 4096
#define D_DIM 256

#define TM 64        // rows per block
#define TK 128       // codes per k-iteration
#define TD 64        // d-chunk
#define PAD 68       // LDS row pitch (64+4 floats): breaks power-of-2 bank stride

// native clang vector type: __builtin_nontemporal_store rejects HIP's float4 class
typedef float f32x4 __attribute__((ext_vector_type(4)));

__launch_bounds__(256, 2)
__global__ void vq_argmin(const float* __restrict__ z_e,
                          const float* __restrict__ embed,
                          float* __restrict__ out) {
    __shared__ float zs[TM * PAD];        // 17408 B
    __shared__ float es[TK * PAD];        // 34816 B
    __shared__ float e2part[TK][2];       // 1024 B
    __shared__ float redv[TM][17];
    __shared__ int   redi[TM][17];

    const int t    = threadIdx.x;
    const int ty   = t >> 4;    // 0..15
    const int tx   = t & 15;    // 0..15
    const int row0 = blockIdx.x * TM;

    const int zrow = t >> 2;    // 0..63, 4 threads/row, 16 floats each
    const int zseg = t & 3;
    const int erow = t >> 1;    // 0..127, 2 threads/row, 32 floats each
    const int eseg = t & 1;

    float best_val[4];
    int   best_idx[4];
#pragma unroll
    for (int r = 0; r < 4; ++r) { best_val[r] = 3.0e38f; best_idx[r] = 0; }

    for (int kc = 0; kc < K_CODE; kc += TK) {
        float acc[4][8];
#pragma unroll
        for (int r = 0; r < 4; ++r)
#pragma unroll
            for (int c = 0; c < 8; ++c) acc[r][c] = 0.0f;

#pragma unroll 1
        for (int dc = 0; dc < D_DIM; dc += TD) {
            __syncthreads();   // protect LDS tiles from previous readers
            if (dc == 0) e2part[erow][eseg] = 0.0f;

            // stage z tile: 64 x 64 floats
            {
                const float* src = z_e + (size_t)(row0 + zrow) * D_DIM + dc + zseg * 16;
                float* dst = &zs[zrow * PAD + zseg * 16];
#pragma unroll
                for (int j = 0; j < 4; ++j)
                    *(float4*)(dst + j * 4) = *(const float4*)(src + j * 4);
            }
            // stage e tile: 128 x 64 floats, accumulate ||e||^2 partials
            {
                const float* src = embed + (size_t)(kc + erow) * D_DIM + dc + eseg * 32;
                float* dst = &es[erow * PAD + eseg * 32];
                float s = 0.0f;
#pragma unroll
                for (int j = 0; j < 8; ++j) {
                    float4 v = *(const float4*)(src + j * 4);
                    *(float4*)(dst + j * 4) = v;
                    s += v.x * v.x + v.y * v.y + v.z * v.z + v.w * v.w;
                }
                e2part[erow][eseg] += s;
            }
            __syncthreads();

            // 4x8 register tile. unroll 1: one iteration already has 12 ds_read_b128
            // + 128 FMAs of ILP; full unroll spilled (round-3: 22.6 GB scratch).
#pragma unroll 1
            for (int g = 0; g < 16; ++g) {
                float4 za[4];
#pragma unroll
                for (int r = 0; r < 4; ++r)
                    za[r] = *(const float4*)&zs[(r * 16 + ty) * PAD + g * 4];
                float4 ea[8];
#pragma unroll
                for (int c = 0; c < 8; ++c)
                    ea[c] = *(const float4*)&es[(c * 16 + tx) * PAD + g * 4];
#pragma unroll
                for (int r = 0; r < 4; ++r)
#pragma unroll
                    for (int c = 0; c < 8; ++c)
                        acc[r][c] += za[r].x * ea[c].x + za[r].y * ea[c].y
                                   + za[r].z * ea[c].z + za[r].w * ea[c].w;
            }
        }

        // val = ||e||^2 - 2 z.e ; strict < keeps first occurrence
#pragma unroll
        for (int c = 0; c < 8; ++c) {
            const int kl = c * 16 + tx;
            const float e2v = e2part[kl][0] + e2part[kl][1];
            const int kg = kc + kl;
#pragma unroll
            for (int r = 0; r < 4; ++r) {
                const float val = e2v - 2.0f * acc[r][c];
                if (val < best_val[r]) { best_val[r] = val; best_idx[r] = kg; }
            }
        }
    }

    // cross-thread (tx) reduction per row; tie -> smaller index (numpy argmin)
    __syncthreads();
#pragma unroll
    for (int r = 0; r < 4; ++r) {
        const int row = r * 16 + ty;
        redv[row][tx] = best_val[r];
        redi[row][tx] = best_idx[r];
    }
    __syncthreads();
    if (t < TM) {
        float bv = redv[t][0];
        int   bi = redi[t][0];
#pragma unroll
        for (int j = 1; j < 16; ++j) {
            const float v = redv[t][j];
            const int   i2 = redi[t][j];
            if (v < bv || (v == bv && i2 < bi)) { bv = v; bi = i2; }
        }
        out[(size_t)N_TOK * D_DIM + (size_t)(row0 + t)] = (float)bi;  // idx as float
    }
}

// Epilogue: pure streaming writes. 32 rows/block, 4 waves -> 8 rows/wave.
// idx values staged through LDS so the store stream has no dependent scalar loads.
__launch_bounds__(256, 2)
__global__ void vq_epilogue(const float* __restrict__ embed,
                            float* __restrict__ out) {
    __shared__ int bks[32];
    const int t    = threadIdx.x;
    const int w    = t >> 6;
    const int lane = t & 63;
    const int row0 = blockIdx.x * 32;

    const float* idxf = out + (size_t)N_TOK * D_DIM;
    float* zq = out;
    float* oh = out + (size_t)N_TOK * D_DIM + N_TOK;

    if (t < 32) bks[t] = (int)idxf[row0 + t];
    __syncthreads();

#pragma unroll 1
    for (int rr = 0; rr < 8; ++rr) {
        const int r   = rr * 4 + w;
        const int row = row0 + r;
        const int bk  = bks[r];

        // z_q row: 64 lanes x float4 = 256 floats (embed row is L2-hot)
        f32x4 v = *(const f32x4*)&embed[(size_t)bk * D_DIM + lane * 4];
        __builtin_nontemporal_store(v, (f32x4*)&zq[(size_t)row * D_DIM + lane * 4]);

        // one_hot row: 16 x 1KB coalesced nontemporal stores
        float* ohrow = &oh[(size_t)row * K_CODE];
#pragma unroll
        for (int g = 0; g < 16; ++g) {
            const int base = (g * 64 + lane) * 4;
            f32x4 u;
            u.x = (bk == base    ) ? 1.0f : 0.0f;
            u.y = (bk == base + 1) ? 1.0f : 0.0f;
            u.z = (bk == base + 2) ? 1.0f : 0.0f;
            u.w = (bk == base + 3) ? 1.0f : 0.0f;
            __builtin_nontemporal_store(u, (f32x4*)&ohrow[base]);
        }
    }
}

extern "C" void kernel_launch(void* const* d_in, const int* in_sizes, int n_in,
                              void* d_out, int out_size, void* d_ws, size_t ws_size,
                              hipStream_t stream) {
    const float* z_e   = (const float*)d_in[0];
    const float* embed = (const float*)d_in[1];
    float* out = (float*)d_out;

    hipLaunchKernelGGL(vq_argmin, dim3(N_TOK / TM), dim3(256), 0, stream,
                       z_e, embed, out);
    hipLaunchKernelGGL(vq_epilogue, dim3(N_TOK / 32), dim3(256), 0, stream,
                       embed, out);
}

// Round 5
// 992.303 us; speedup vs baseline: 11.7228x; 1.7476x over previous
//
#include <hip/hip_runtime.h>

// VQ-VAE quantization: N=32768, K=4096, D=256, fp32.
// Outputs (concat float32): z_q [N*D], idx [N] (as float), one_hot [N*K].
//
// Round-5: MFMA via exact 3-way bf16 split. x = xh+xm+xl is EXACT (3x8 mantissa
// bits cover fp32's 24). Products kept: hh,hm,mh,mm,hl,lh -> dropped terms
// ~2^-24 relative (~2e-6 on distances), below the fp32 reference's own rounding.
// Rank by (||e||^2 - 2 z.e); ||z||^2 drops out of argmin.
//
// Pipeline: vq_prep (embed -> fragment-ordered bf16 h/m/l planes + e2, stored in
// the TAIL of the one_hot output region as scratch; epilogue overwrites it last)
// -> vq_argmin_mfma (6-product MFMA accumulate, lane-linear ds_read_b128)
// -> vq_epilogue (streaming z_q + one_hot, nontemporal).
// fp32-vector path floor was ~1ms (LDS-issue+VALU co-bound, r4: 67% VALUBusy);
// MFMA floor = 6 x 68.7GF / 2.4PF ~= 199 us.

#define N_TOK 32768
#define K_CODE 4096
#define D_DIM 256
#define BM 64                 // rows per argmin block

typedef float f32x4 __attribute__((ext_vector_type(4)));
typedef short s16x8 __attribute__((ext_vector_type(8)));
typedef int   i32x4 __attribute__((ext_vector_type(4)));

// d_out tail scratch: e_frags ushort[3*K*D] = 6,291,456 B, then e2 float[K]
#define OUT_FLOATS 142639104u          // N*D + N + N*K
#define SCR_FLOATS 1576960u            // 3*K*D/2 + K
#define SCR_OFF    (OUT_FLOATS - SCR_FLOATS)      // 141,062,144
#define EFRAG_SHORTS (3u * K_CODE * D_DIM)        // 3,145,728

// RTNE float->bf16 (finite inputs); split is exact.
static __device__ __forceinline__ unsigned short f2bf(float f) {
    unsigned int u = __float_as_uint(f);
    u = (u + 0x7fffu + ((u >> 16) & 1u)) >> 16;
    return (unsigned short)u;
}
static __device__ __forceinline__ float bf2f(unsigned short b) {
    return __uint_as_float(((unsigned int)b) << 16);
}

// ---------------------------------------------------------------------------
// Prep: decompose embed into fragment-ordered bf16 planes + e2 (deterministic).
// Fragment layout (1KB frags): [ct_g(256)][dc(8)][c(3)][lane(64)][8 bf16],
// where for element e[k][d]: ct_g=k>>4, n=k&15, dc=d>>5, quad=(d>>3)&3, j=d&7,
// lane=quad*16+n  (MFMA 16x16x32 operand order: entity=lane&15, k=quad*8+j).
// ---------------------------------------------------------------------------
__global__ __launch_bounds__(256) void vq_prep(const float* __restrict__ embed,
                                               float* __restrict__ out) {
    __shared__ float part[8][33];
    unsigned short* escr = (unsigned short*)(out + SCR_OFF);
    float* e2g = out + SCR_OFF + (EFRAG_SHORTS / 2);

    const int t    = threadIdx.x;
    const int cl   = t >> 5;          // code_local 0..7
    const int r32  = t & 31;
    const int dc   = r32 >> 2;
    const int quad = r32 & 3;
    const int k    = blockIdx.x * 8 + cl;

    const float* src = embed + (size_t)k * D_DIM + dc * 32 + quad * 8;
    float x[8];
    *(float4*)(x)     = *(const float4*)(src);
    *(float4*)(x + 4) = *(const float4*)(src + 4);

    s16x8 hv, mv, lv;
    float s2 = 0.0f;
#pragma unroll
    for (int j = 0; j < 8; ++j) {
        const float xx = x[j];
        s2 += xx * xx;
        const unsigned short bh = f2bf(xx);
        const float r1 = xx - bf2f(bh);
        const unsigned short bm = f2bf(r1);
        const float r2 = r1 - bf2f(bm);
        const unsigned short bl = f2bf(r2);
        hv[j] = (short)bh; mv[j] = (short)bm; lv[j] = (short)bl;
    }

    const int ct_g = k >> 4;
    const int lane = quad * 16 + (k & 15);
    const size_t base = ((size_t)(ct_g * 8 + dc) * 3) * 512 + lane * 8;
    *(s16x8*)&escr[base]         = hv;   // c=0
    *(s16x8*)&escr[base + 512]   = mv;   // c=1
    *(s16x8*)&escr[base + 1024]  = lv;   // c=2

    part[cl][r32] = s2;
    __syncthreads();
    if (t < 8) {
        float s = 0.0f;
#pragma unroll
        for (int j = 0; j < 32; ++j) s += part[t][j];   // fixed order: deterministic
        e2g[blockIdx.x * 8 + t] = s;
    }
}

// ---------------------------------------------------------------------------
// Argmin: 512 threads = 8 waves (2 row-groups x 4 code-groups), 64 rows/block.
// A (z, 3 planes) converted once into LDS fragment order (96 KB).
// Per (kc: 16 x 256 codes, dc: 8 x 32 dims): stage 48KB B frags, each wave
// 18 lane-linear ds_read_b128 + 48 MFMA (2 rt x 4 u x 6 passes).
// ---------------------------------------------------------------------------
__global__ __launch_bounds__(512, 2)
void vq_argmin_mfma(const float* __restrict__ z_e, float* __restrict__ out) {
    __shared__ __align__(16) short As[49152];   // 96 KB: [(c*4+rtile)*8+dc]*512 + lane*8
    __shared__ __align__(16) short Bs[24576];   // 48 KB: [(c*16+ctile)]*512 + lane*8
    __shared__ float e2s[256];
    __shared__ float redv[64][4];
    __shared__ int   redi[64][4];

    const unsigned short* escr = (const unsigned short*)(out + SCR_OFF);
    const float* e2g = out + SCR_OFF + (EFRAG_SHORTS / 2);

    const int t    = threadIdx.x;
    const int w    = t >> 6;        // wave 0..7
    const int wr   = w >> 2;        // row-group 0..1 (32 rows each)
    const int wc   = w & 3;         // code-group 0..3 (64 codes each)
    const int lane = t & 63;
    const int n    = lane & 15;
    const int quad = lane >> 4;
    const int row0 = blockIdx.x * BM;

    // ---- stage + convert A (once) ----
#pragma unroll
    for (int i = 0; i < 4; ++i) {
        const int run  = t + 512 * i;           // (row, dc, quad): 64*8*4 = 2048 runs
        const int qs   = run & 3;
        const int dcs  = (run >> 2) & 7;
        const int row  = run >> 5;
        const float* src = z_e + (size_t)(row0 + row) * D_DIM + dcs * 32 + qs * 8;
        float x[8];
        *(float4*)(x)     = *(const float4*)(src);
        *(float4*)(x + 4) = *(const float4*)(src + 4);
        s16x8 hv, mv, lv;
#pragma unroll
        for (int j = 0; j < 8; ++j) {
            const float xx = x[j];
            const unsigned short bh = f2bf(xx);
            const float r1 = xx - bf2f(bh);
            const unsigned short bm = f2bf(r1);
            const float r2 = r1 - bf2f(bm);
            hv[j] = (short)bh; mv[j] = (short)bm; lv[j] = (short)f2bf(r2);
        }
        const int rtile = row >> 4;
        const int ls    = qs * 16 + (row & 15);
        *(s16x8*)&As[((0 * 4 + rtile) * 8 + dcs) * 512 + ls * 8] = hv;
        *(s16x8*)&As[((1 * 4 + rtile) * 8 + dcs) * 512 + ls * 8] = mv;
        *(s16x8*)&As[((2 * 4 + rtile) * 8 + dcs) * 512 + ls * 8] = lv;
    }

    float bv[8];
    int   bidx[8];
#pragma unroll
    for (int s = 0; s < 8; ++s) { bv[s] = 3.0e38f; bidx[s] = 0; }

#pragma unroll 1
    for (int kt = 0; kt < 16; ++kt) {
        const int kc = kt * 256;
        __syncthreads();                       // protect e2s & Bs from prev readers
        if (t < 256) e2s[t] = e2g[kc + t];

        f32x4 acc[2][4];
#pragma unroll
        for (int rt = 0; rt < 2; ++rt)
#pragma unroll
            for (int u = 0; u < 4; ++u) acc[rt][u] = (f32x4){0.f, 0.f, 0.f, 0.f};

#pragma unroll 1
        for (int dc = 0; dc < 8; ++dc) {
            if (dc) __syncthreads();           // protect Bs (dc=0 covered above)
            // stage B: 48 frags x 1KB; thread does 6 x 16B chunks, coalesced
#pragma unroll
            for (int s = 0; s < 6; ++s) {
                const int chunk = t + 512 * s;
                const int frag  = chunk >> 6;          // 0..47
                const int lf    = chunk & 63;
                const int c     = frag >> 4;           // 0..2
                const int ctile = frag & 15;
                const int ct_g  = (kc >> 4) + ctile;
                const i32x4 v = *(const i32x4*)&escr[((size_t)(ct_g * 8 + dc) * 3 + c) * 512 + lf * 8];
                *(i32x4*)&Bs[(c * 16 + ctile) * 512 + lf * 8] = v;
            }
            __syncthreads();

            s16x8 af[2][3], bfm[4][3];
#pragma unroll
            for (int rt = 0; rt < 2; ++rt)
#pragma unroll
                for (int c = 0; c < 3; ++c)
                    af[rt][c] = *(const s16x8*)&As[((c * 4 + wr * 2 + rt) * 8 + dc) * 512 + lane * 8];
#pragma unroll
            for (int u = 0; u < 4; ++u)
#pragma unroll
                for (int c = 0; c < 3; ++c)
                    bfm[u][c] = *(const s16x8*)&Bs[(c * 16 + wc * 4 + u) * 512 + lane * 8];

#pragma unroll
            for (int rt = 0; rt < 2; ++rt)
#pragma unroll
                for (int u = 0; u < 4; ++u) {
                    f32x4 a = acc[rt][u];
                    a = __builtin_amdgcn_mfma_f32_16x16x32_bf16(af[rt][0], bfm[u][0], a, 0, 0, 0);
                    a = __builtin_amdgcn_mfma_f32_16x16x32_bf16(af[rt][0], bfm[u][1], a, 0, 0, 0);
                    a = __builtin_amdgcn_mfma_f32_16x16x32_bf16(af[rt][1], bfm[u][0], a, 0, 0, 0);
                    a = __builtin_amdgcn_mfma_f32_16x16x32_bf16(af[rt][1], bfm[u][1], a, 0, 0, 0);
                    a = __builtin_amdgcn_mfma_f32_16x16x32_bf16(af[rt][0], bfm[u][2], a, 0, 0, 0);
                    a = __builtin_amdgcn_mfma_f32_16x16x32_bf16(af[rt][2], bfm[u][0], a, 0, 0, 0);
                    acc[rt][u] = a;
                }
        }

        // merge: val = e2 - 2*dot ; within-lane codes ascend (kt, u) -> strict <
#pragma unroll
        for (int u = 0; u < 4; ++u) {
            const int   code = kc + wc * 64 + u * 16 + n;
            const float e2v  = e2s[wc * 64 + u * 16 + n];
#pragma unroll
            for (int rt = 0; rt < 2; ++rt)
#pragma unroll
                for (int r = 0; r < 4; ++r) {
                    const float val = fmaf(-2.0f, acc[rt][u][r], e2v);
                    const int slot = rt * 4 + r;
                    if (val < bv[slot]) { bv[slot] = val; bidx[slot] = code; }
                }
        }
    }

    // butterfly over the 16 lanes of each quad-group (codes interleave -> lex tie-break)
#pragma unroll
    for (int slot = 0; slot < 8; ++slot) {
#pragma unroll
        for (int mask = 1; mask < 16; mask <<= 1) {
            const float ov = __shfl_xor(bv[slot], mask);
            const int   oi = __shfl_xor(bidx[slot], mask);
            if (ov < bv[slot] || (ov == bv[slot] && oi < bidx[slot])) {
                bv[slot] = ov; bidx[slot] = oi;
            }
        }
    }
    if (n == 0) {
#pragma unroll
        for (int rt = 0; rt < 2; ++rt)
#pragma unroll
            for (int r = 0; r < 4; ++r) {
                const int row_local = wr * 32 + rt * 16 + quad * 4 + r;
                redv[row_local][wc] = bv[rt * 4 + r];
                redi[row_local][wc] = bidx[rt * 4 + r];
            }
    }
    __syncthreads();
    if (t < 64) {
        float v = redv[t][0];
        int  bi = redi[t][0];
#pragma unroll
        for (int j = 1; j < 4; ++j) {
            const float v2 = redv[t][j];
            const int   i2 = redi[t][j];
            if (v2 < v || (v2 == v && i2 < bi)) { v = v2; bi = i2; }
        }
        out[(size_t)N_TOK * D_DIM + (size_t)(row0 + t)] = (float)bi;
    }
}

// ---------------------------------------------------------------------------
// Epilogue: streaming z_q + one_hot (overwrites the scratch tail last).
// ---------------------------------------------------------------------------
__launch_bounds__(256, 2)
__global__ void vq_epilogue(const float* __restrict__ embed,
                            float* __restrict__ out) {
    __shared__ int bks[32];
    const int t    = threadIdx.x;
    const int w    = t >> 6;
    const int lane = t & 63;
    const int row0 = blockIdx.x * 32;

    const float* idxf = out + (size_t)N_TOK * D_DIM;
    float* zq = out;
    float* oh = out + (size_t)N_TOK * D_DIM + N_TOK;

    if (t < 32) bks[t] = (int)idxf[row0 + t];
    __syncthreads();

#pragma unroll 1
    for (int rr = 0; rr < 8; ++rr) {
        const int r   = rr * 4 + w;
        const int row = row0 + r;
        const int bk  = bks[r];

        f32x4 v = *(const f32x4*)&embed[(size_t)bk * D_DIM + lane * 4];
        __builtin_nontemporal_store(v, (f32x4*)&zq[(size_t)row * D_DIM + lane * 4]);

        float* ohrow = &oh[(size_t)row * K_CODE];
#pragma unroll
        for (int g = 0; g < 16; ++g) {
            const int base = (g * 64 + lane) * 4;
            f32x4 u;
            u.x = (bk == base    ) ? 1.0f : 0.0f;
            u.y = (bk == base + 1) ? 1.0f : 0.0f;
            u.z = (bk == base + 2) ? 1.0f : 0.0f;
            u.w = (bk == base + 3) ? 1.0f : 0.0f;
            __builtin_nontemporal_store(u, (f32x4*)&ohrow[base]);
        }
    }
}

extern "C" void kernel_launch(void* const* d_in, const int* in_sizes, int n_in,
                              void* d_out, int out_size, void* d_ws, size_t ws_size,
                              hipStream_t stream) {
    const float* z_e   = (const float*)d_in[0];
    const float* embed = (const float*)d_in[1];
    float* out = (float*)d_out;

    hipLaunchKernelGGL(vq_prep,        dim3(K_CODE / 8),  dim3(256), 0, stream, embed, out);
    hipLaunchKernelGGL(vq_argmin_mfma, dim3(N_TOK / BM),  dim3(512), 0, stream, z_e, out);
    hipLaunchKernelGGL(vq_epilogue,    dim3(N_TOK / 32),  dim3(256), 0, stream, embed, out);
}

// Round 6
// 874.112 us; speedup vs baseline: 13.3079x; 1.1352x over previous
//
#include <hip/hip_runtime.h>

// VQ-VAE quantization: N=32768, K=4096, D=256, fp32.
// Outputs (concat float32): z_q [N*D], idx [N] (as float), one_hot [N*K].
//
// Exact 3-way bf16 split (x=xh+xm+xl, exact for fp32's 24-bit mantissa);
// 6 MFMA products (hh,hm,mh,mm,hl,lh); rank by (||e||^2 - 2 z.e).
//
// Round-6: barrier-free MFMA main loop. r5 counters: MfmaUtil 38%, LDS pipe
// (192 b128-instr x 12cyc = 4.6k cyc/CU/dc) > MFMA (3.7k) + 2 barriers/dc; and
// the B LDS staging had ZERO reuse (each frag read by exactly one wave).
// Fix: B fragments + e2 read directly from the fragment-ordered global scratch
// (6.3MB, L2/L3-resident, lane-linear dwordx4) -> B traffic moves to VMEM pipe,
// no staging writes, no barriers in the kt/dc loops. LDS holds only A (96KB).

#define N_TOK 32768
#define K_CODE 4096
#define D_DIM 256
#define BM 64                 // rows per argmin block

typedef float f32x4 __attribute__((ext_vector_type(4)));
typedef short s16x8 __attribute__((ext_vector_type(8)));
typedef int   i32x4 __attribute__((ext_vector_type(4)));

// d_out tail scratch: e_frags ushort[3*K*D] = 6,291,456 B, then e2 float[K]
#define OUT_FLOATS 142639104u          // N*D + N + N*K
#define SCR_FLOATS 1576960u            // 3*K*D/2 + K
#define SCR_OFF    (OUT_FLOATS - SCR_FLOATS)      // inside one_hot; epilogue overwrites last
#define EFRAG_SHORTS (3u * K_CODE * D_DIM)

// RTNE float->bf16 (finite inputs); 3-way split is exact.
static __device__ __forceinline__ unsigned short f2bf(float f) {
    unsigned int u = __float_as_uint(f);
    u = (u + 0x7fffu + ((u >> 16) & 1u)) >> 16;
    return (unsigned short)u;
}
static __device__ __forceinline__ float bf2f(unsigned short b) {
    return __uint_as_float(((unsigned int)b) << 16);
}

// ---------------------------------------------------------------------------
// Prep: embed -> fragment-ordered bf16 h/m/l planes + e2.
// Frag layout (1KB): [ct_g(256)][dc(8)][c(3)][lane(64)][8 bf16];
// element e[k][d]: ct_g=k>>4, n=k&15, dc=d>>5, quad=(d>>3)&3, j=d&7, lane=quad*16+n.
// ---------------------------------------------------------------------------
__global__ __launch_bounds__(256) void vq_prep(const float* __restrict__ embed,
                                               float* __restrict__ out) {
    __shared__ float part[8][33];
    unsigned short* escr = (unsigned short*)(out + SCR_OFF);
    float* e2g = out + SCR_OFF + (EFRAG_SHORTS / 2);

    const int t    = threadIdx.x;
    const int cl   = t >> 5;
    const int r32  = t & 31;
    const int dc   = r32 >> 2;
    const int quad = r32 & 3;
    const int k    = blockIdx.x * 8 + cl;

    const float* src = embed + (size_t)k * D_DIM + dc * 32 + quad * 8;
    float x[8];
    *(float4*)(x)     = *(const float4*)(src);
    *(float4*)(x + 4) = *(const float4*)(src + 4);

    s16x8 hv, mv, lv;
    float s2 = 0.0f;
#pragma unroll
    for (int j = 0; j < 8; ++j) {
        const float xx = x[j];
        s2 += xx * xx;
        const unsigned short bh = f2bf(xx);
        const float r1 = xx - bf2f(bh);
        const unsigned short bm = f2bf(r1);
        const float r2 = r1 - bf2f(bm);
        hv[j] = (short)bh; mv[j] = (short)bm; lv[j] = (short)f2bf(r2);
    }

    const int ct_g = k >> 4;
    const int lane = quad * 16 + (k & 15);
    const size_t base = ((size_t)(ct_g * 8 + dc) * 3) * 512 + lane * 8;
    *(s16x8*)&escr[base]        = hv;
    *(s16x8*)&escr[base + 512]  = mv;
    *(s16x8*)&escr[base + 1024] = lv;

    part[cl][r32] = s2;
    __syncthreads();
    if (t < 8) {
        float s = 0.0f;
#pragma unroll
        for (int j = 0; j < 32; ++j) s += part[t][j];   // fixed order: deterministic
        e2g[blockIdx.x * 8 + t] = s;
    }
}

// ---------------------------------------------------------------------------
// Argmin: 512 thr = 8 waves, 64 rows/block, grid 512. LDS = A only (96KB ->
// 1 block/CU, 8 waves). Wave w covers all 4 row-tiles x 2 ctiles (ctile=w*2+u).
// Per dc: 12 LDS af reads + 6 global bfm reads + 48 MFMA, NO barriers.
// ---------------------------------------------------------------------------
__global__ __launch_bounds__(512, 2)
void vq_argmin_mfma(const float* __restrict__ z_e, float* __restrict__ out) {
    __shared__ __align__(16) short As[49152];   // [(c*4+rtile)*8+dc]*512 + ls*8
    __shared__ float redv[64][9];
    __shared__ int   redi[64][9];

    const unsigned short* escr = (const unsigned short*)(out + SCR_OFF);
    const float* e2g = out + SCR_OFF + (EFRAG_SHORTS / 2);

    const int t    = threadIdx.x;
    const int w    = t >> 6;        // wave 0..7 = code-group (32 codes each)
    const int lane = t & 63;
    const int n    = lane & 15;
    const int quad = lane >> 4;
    const int row0 = blockIdx.x * BM;

    // ---- stage + convert A (once) ----
#pragma unroll
    for (int i = 0; i < 4; ++i) {
        const int run  = t + 512 * i;           // (row, dcs, qs): 64*8*4 = 2048
        const int qs   = run & 3;
        const int dcs  = (run >> 2) & 7;
        const int row  = run >> 5;
        const float* src = z_e + (size_t)(row0 + row) * D_DIM + dcs * 32 + qs * 8;
        float x[8];
        *(float4*)(x)     = *(const float4*)(src);
        *(float4*)(x + 4) = *(const float4*)(src + 4);
        s16x8 hv, mv, lv;
#pragma unroll
        for (int j = 0; j < 8; ++j) {
            const float xx = x[j];
            const unsigned short bh = f2bf(xx);
            const float r1 = xx - bf2f(bh);
            const unsigned short bm = f2bf(r1);
            hv[j] = (short)bh; mv[j] = (short)bm; lv[j] = (short)f2bf(r1 - bf2f(bm));
        }
        const int rtile = row >> 4;
        const int ls    = qs * 16 + (row & 15);
        *(s16x8*)&As[((0 * 4 + rtile) * 8 + dcs) * 512 + ls * 8] = hv;
        *(s16x8*)&As[((1 * 4 + rtile) * 8 + dcs) * 512 + ls * 8] = mv;
        *(s16x8*)&As[((2 * 4 + rtile) * 8 + dcs) * 512 + ls * 8] = lv;
    }
    __syncthreads();

    float bv[16];
    int   bidx[16];
#pragma unroll
    for (int s = 0; s < 16; ++s) { bv[s] = 3.0e38f; bidx[s] = 0; }

#pragma unroll 1
    for (int kt = 0; kt < 16; ++kt) {
        f32x4 acc[4][2];
#pragma unroll
        for (int rt = 0; rt < 4; ++rt)
#pragma unroll
            for (int u = 0; u < 2; ++u) acc[rt][u] = (f32x4){0.f, 0.f, 0.f, 0.f};

#pragma unroll 1
        for (int dc = 0; dc < 8; ++dc) {
            // B fragments straight from global scratch (L2/L3-hot, lane-linear 1KB)
            s16x8 bfm[2][3];
#pragma unroll
            for (int u = 0; u < 2; ++u) {
                const int ct_g = kt * 16 + w * 2 + u;
#pragma unroll
                for (int c = 0; c < 3; ++c)
                    bfm[u][c] = *(const s16x8*)&escr[((size_t)(ct_g * 8 + dc) * 3 + c) * 512 + lane * 8];
            }
#pragma unroll
            for (int rt = 0; rt < 4; ++rt) {
                s16x8 af0 = *(const s16x8*)&As[((0 * 4 + rt) * 8 + dc) * 512 + lane * 8];
                s16x8 af1 = *(const s16x8*)&As[((1 * 4 + rt) * 8 + dc) * 512 + lane * 8];
                s16x8 af2 = *(const s16x8*)&As[((2 * 4 + rt) * 8 + dc) * 512 + lane * 8];
#pragma unroll
                for (int u = 0; u < 2; ++u) {
                    f32x4 a = acc[rt][u];
                    a = __builtin_amdgcn_mfma_f32_16x16x32_bf16(af0, bfm[u][0], a, 0, 0, 0);
                    a = __builtin_amdgcn_mfma_f32_16x16x32_bf16(af0, bfm[u][1], a, 0, 0, 0);
                    a = __builtin_amdgcn_mfma_f32_16x16x32_bf16(af1, bfm[u][0], a, 0, 0, 0);
                    a = __builtin_amdgcn_mfma_f32_16x16x32_bf16(af1, bfm[u][1], a, 0, 0, 0);
                    a = __builtin_amdgcn_mfma_f32_16x16x32_bf16(af0, bfm[u][2], a, 0, 0, 0);
                    a = __builtin_amdgcn_mfma_f32_16x16x32_bf16(af2, bfm[u][0], a, 0, 0, 0);
                    acc[rt][u] = a;
                }
            }
        }

        // merge: val = e2 - 2*dot. Codes ascend over (kt, u) per slot -> strict <
        // keeps first occurrence. e2 read direct (16 consecutive floats, coalesced).
#pragma unroll
        for (int u = 0; u < 2; ++u) {
            const int  code = kt * 256 + (w * 2 + u) * 16 + n;
            const float e2v = e2g[code];
#pragma unroll
            for (int rt = 0; rt < 4; ++rt)
#pragma unroll
                for (int r = 0; r < 4; ++r) {
                    const float val = fmaf(-2.0f, acc[rt][u][r], e2v);
                    const int slot = rt * 4 + r;
                    if (val < bv[slot]) { bv[slot] = val; bidx[slot] = code; }
                }
        }
    }

    // butterfly over 16 lanes (codes interleave mod 16 -> lex tie-break)
#pragma unroll
    for (int slot = 0; slot < 16; ++slot) {
#pragma unroll
        for (int mask = 1; mask < 16; mask <<= 1) {
            const float ov = __shfl_xor(bv[slot], mask);
            const int   oi = __shfl_xor(bidx[slot], mask);
            if (ov < bv[slot] || (ov == bv[slot] && oi < bidx[slot])) {
                bv[slot] = ov; bidx[slot] = oi;
            }
        }
    }
    if (n == 0) {
#pragma unroll
        for (int rt = 0; rt < 4; ++rt)
#pragma unroll
            for (int r = 0; r < 4; ++r) {
                const int row_local = rt * 16 + quad * 4 + r;   // C/D: row=quad*4+reg
                redv[row_local][w] = bv[rt * 4 + r];
                redi[row_local][w] = bidx[rt * 4 + r];
            }
    }
    __syncthreads();
    if (t < 64) {
        float v = redv[t][0];
        int  bi = redi[t][0];
#pragma unroll
        for (int j = 1; j < 8; ++j) {
            const float v2 = redv[t][j];
            const int   i2 = redi[t][j];
            if (v2 < v || (v2 == v && i2 < bi)) { v = v2; bi = i2; }
        }
        out[(size_t)N_TOK * D_DIM + (size_t)(row0 + t)] = (float)bi;
    }
}

// ---------------------------------------------------------------------------
// Epilogue: streaming z_q + one_hot (overwrites scratch tail). 2048 blocks x
// 16 rows; high occupancy (launch_bounds min 8 waves/EU) to deepen store queue.
// ---------------------------------------------------------------------------
__launch_bounds__(256, 8)
__global__ void vq_epilogue(const float* __restrict__ embed,
                            float* __restrict__ out) {
    __shared__ int bks[16];
    const int t    = threadIdx.x;
    const int w    = t >> 6;
    const int lane = t & 63;
    const int row0 = blockIdx.x * 16;

    const float* idxf = out + (size_t)N_TOK * D_DIM;
    float* zq = out;
    float* oh = out + (size_t)N_TOK * D_DIM + N_TOK;

    if (t < 16) bks[t] = (int)idxf[row0 + t];
    __syncthreads();

#pragma unroll 1
    for (int rr = 0; rr < 4; ++rr) {
        const int r   = rr * 4 + w;
        const int row = row0 + r;
        const int bk  = bks[r];

        f32x4 v = *(const f32x4*)&embed[(size_t)bk * D_DIM + lane * 4];
        __builtin_nontemporal_store(v, (f32x4*)&zq[(size_t)row * D_DIM + lane * 4]);

        float* ohrow = &oh[(size_t)row * K_CODE];
#pragma unroll
        for (int g = 0; g < 16; ++g) {
            const int base = (g * 64 + lane) * 4;
            f32x4 u;
            u.x = (bk == base    ) ? 1.0f : 0.0f;
            u.y = (bk == base + 1) ? 1.0f : 0.0f;
            u.z = (bk == base + 2) ? 1.0f : 0.0f;
            u.w = (bk == base + 3) ? 1.0f : 0.0f;
            __builtin_nontemporal_store(u, (f32x4*)&ohrow[base]);
        }
    }
}

extern "C" void kernel_launch(void* const* d_in, const int* in_sizes, int n_in,
                              void* d_out, int out_size, void* d_ws, size_t ws_size,
                              hipStream_t stream) {
    const float* z_e   = (const float*)d_in[0];
    const float* embed = (const float*)d_in[1];
    float* out = (float*)d_out;

    hipLaunchKernelGGL(vq_prep,        dim3(K_CODE / 8), dim3(256), 0, stream, embed, out);
    hipLaunchKernelGGL(vq_argmin_mfma, dim3(N_TOK / BM), dim3(512), 0, stream, z_e, out);
    hipLaunchKernelGGL(vq_epilogue,    dim3(N_TOK / 16), dim3(256), 0, stream, embed, out);
}

// Round 7
// 853.912 us; speedup vs baseline: 13.6227x; 1.0237x over previous
//
#include <hip/hip_runtime.h>

// VQ-VAE quantization: N=32768, K=4096, D=256, fp32.
// Outputs (concat float32): z_q [N*D], idx [N] (as float), one_hot [N*K].
//
// Exact 3-way bf16 split (x=xh+xm+xl, exact for fp32's 24-bit mantissa);
// 6 MFMA products (hh,hm,mh,mm,hl,lh); rank by (||e||^2 - 2 z.e).
//
// Round-7: fuse output writes into the argmin tail (nontemporal -> no L2 thrash
// of the B scratch) and register-double-buffer the B global loads across a
// flattened (kt,dc) loop so L2 latency hides behind MFMA. Scratch sits in the
// one_hot tail; blocks covering rows >= 32320 skip one_hot there and a small
// cleanup kernel rewrites those 448 rows afterwards.

#define N_TOK 32768
#define K_CODE 4096
#define D_DIM 256
#define BM 64

typedef float f32x4 __attribute__((ext_vector_type(4)));
typedef short s16x8 __attribute__((ext_vector_type(8)));

// d_out tail scratch: e_frags ushort[3*K*D] = 6,291,456 B, then e2 float[K]
#define OUT_FLOATS 142639104u          // N*D + N + N*K
#define SCR_FLOATS 1576960u            // 3*K*D/2 + K
#define SCR_OFF    (OUT_FLOATS - SCR_FLOATS)
#define EFRAG_SHORTS (3u * K_CODE * D_DIM)
#define OH_SAFE_ROWS 32320             // rows >= this: one_hot overlaps scratch region

static __device__ __forceinline__ unsigned short f2bf(float f) {
    unsigned int u = __float_as_uint(f);
    u = (u + 0x7fffu + ((u >> 16) & 1u)) >> 16;
    return (unsigned short)u;
}
static __device__ __forceinline__ float bf2f(unsigned short b) {
    return __uint_as_float(((unsigned int)b) << 16);
}

// ---------------------------------------------------------------------------
// Prep: embed -> fragment-ordered bf16 h/m/l planes + e2.
// Frag layout (1KB): [ct_g(256)][dc(8)][c(3)][lane(64)][8 bf16];
// e[k][d]: ct_g=k>>4, n=k&15, dc=d>>5, quad=(d>>3)&3, j=d&7, lane=quad*16+n.
// ---------------------------------------------------------------------------
__global__ __launch_bounds__(256) void vq_prep(const float* __restrict__ embed,
                                               float* __restrict__ out) {
    __shared__ float part[8][33];
    unsigned short* escr = (unsigned short*)(out + SCR_OFF);
    float* e2g = out + SCR_OFF + (EFRAG_SHORTS / 2);

    const int t    = threadIdx.x;
    const int cl   = t >> 5;
    const int r32  = t & 31;
    const int dc   = r32 >> 2;
    const int quad = r32 & 3;
    const int k    = blockIdx.x * 8 + cl;

    const float* src = embed + (size_t)k * D_DIM + dc * 32 + quad * 8;
    float x[8];
    *(float4*)(x)     = *(const float4*)(src);
    *(float4*)(x + 4) = *(const float4*)(src + 4);

    s16x8 hv, mv, lv;
    float s2 = 0.0f;
#pragma unroll
    for (int j = 0; j < 8; ++j) {
        const float xx = x[j];
        s2 += xx * xx;
        const unsigned short bh = f2bf(xx);
        const float r1 = xx - bf2f(bh);
        const unsigned short bm = f2bf(r1);
        hv[j] = (short)bh; mv[j] = (short)bm; lv[j] = (short)f2bf(r1 - bf2f(bm));
    }

    const int ct_g = k >> 4;
    const int lane = quad * 16 + (k & 15);
    const size_t base = ((size_t)(ct_g * 8 + dc) * 3) * 512 + lane * 8;
    *(s16x8*)&escr[base]        = hv;
    *(s16x8*)&escr[base + 512]  = mv;
    *(s16x8*)&escr[base + 1024] = lv;

    part[cl][r32] = s2;
    __syncthreads();
    if (t < 8) {
        float s = 0.0f;
#pragma unroll
        for (int j = 0; j < 32; ++j) s += part[t][j];   // fixed order: deterministic
        e2g[blockIdx.x * 8 + t] = s;
    }
}

// ---- helpers for the double-buffered main loop --------------------------
static __device__ __forceinline__ void load_b(const unsigned short* __restrict__ escr,
                                              int kt, int dc, int w, int lane,
                                              s16x8 (&buf)[2][3]) {
#pragma unroll
    for (int u = 0; u < 2; ++u) {
        const int ct_g = kt * 16 + w * 2 + u;
        const unsigned short* p = &escr[((size_t)(ct_g * 8 + dc) * 3) * 512 + lane * 8];
#pragma unroll
        for (int c = 0; c < 3; ++c)
            buf[u][c] = *(const s16x8*)(p + c * 512);
    }
}

static __device__ __forceinline__ void proc_step(const short* As,
        const float* __restrict__ e2g, int kt, int dc, int w, int lane, int n,
        s16x8 (&bfm)[2][3], f32x4 (&acc)[4][2], float (&e2r)[2],
        float (&bv)[16], int (&bidx)[16]) {
    if (dc == 0) {       // prefetch e2 8 steps ahead of its dc==7 use
#pragma unroll
        for (int u = 0; u < 2; ++u) e2r[u] = e2g[kt * 256 + (w * 2 + u) * 16 + n];
    }
#pragma unroll
    for (int rt = 0; rt < 4; ++rt) {
        s16x8 af0 = *(const s16x8*)&As[((0 * 4 + rt) * 8 + dc) * 512 + lane * 8];
        s16x8 af1 = *(const s16x8*)&As[((1 * 4 + rt) * 8 + dc) * 512 + lane * 8];
        s16x8 af2 = *(const s16x8*)&As[((2 * 4 + rt) * 8 + dc) * 512 + lane * 8];
#pragma unroll
        for (int u = 0; u < 2; ++u) {
            f32x4 a = acc[rt][u];
            a = __builtin_amdgcn_mfma_f32_16x16x32_bf16(af0, bfm[u][0], a, 0, 0, 0);
            a = __builtin_amdgcn_mfma_f32_16x16x32_bf16(af0, bfm[u][1], a, 0, 0, 0);
            a = __builtin_amdgcn_mfma_f32_16x16x32_bf16(af1, bfm[u][0], a, 0, 0, 0);
            a = __builtin_amdgcn_mfma_f32_16x16x32_bf16(af1, bfm[u][1], a, 0, 0, 0);
            a = __builtin_amdgcn_mfma_f32_16x16x32_bf16(af0, bfm[u][2], a, 0, 0, 0);
            a = __builtin_amdgcn_mfma_f32_16x16x32_bf16(af2, bfm[u][0], a, 0, 0, 0);
            acc[rt][u] = a;
        }
    }
    if (dc == 7) {   // merge: codes ascend over (kt,u) per slot -> strict < = first occurrence
#pragma unroll
        for (int u = 0; u < 2; ++u) {
            const int code = kt * 256 + (w * 2 + u) * 16 + n;
#pragma unroll
            for (int rt = 0; rt < 4; ++rt)
#pragma unroll
                for (int r = 0; r < 4; ++r) {
                    const float val = fmaf(-2.0f, acc[rt][u][r], e2r[u]);
                    const int slot = rt * 4 + r;
                    if (val < bv[slot]) { bv[slot] = val; bidx[slot] = code; }
                }
        }
#pragma unroll
        for (int rt = 0; rt < 4; ++rt)
#pragma unroll
            for (int u = 0; u < 2; ++u) acc[rt][u] = (f32x4){0.f, 0.f, 0.f, 0.f};
    }
}

// ---------------------------------------------------------------------------
// Argmin + fused outputs: 512 thr = 8 waves, 64 rows/block, grid 512 (1 block/CU,
// 2 rounds). LDS = A only (96KB). Flattened 128-step (kt,dc) loop, ping-pong
// B prefetch. Tail: idx + nontemporal z_q + one_hot (skipped for rows >= 32320).
// ---------------------------------------------------------------------------
__global__ __launch_bounds__(512, 2)
void vq_argmin_mfma(const float* __restrict__ z_e,
                    const float* __restrict__ embed,
                    float* __restrict__ out) {
    __shared__ __align__(16) short As[49152];   // [(c*4+rtile)*8+dc]*512 + ls*8
    __shared__ float redv[64][9];
    __shared__ int   redi[64][9];
    __shared__ int   bk_lds[64];

    const unsigned short* escr = (const unsigned short*)(out + SCR_OFF);
    const float* e2g = out + SCR_OFF + (EFRAG_SHORTS / 2);

    const int t    = threadIdx.x;
    const int w    = t >> 6;
    const int lane = t & 63;
    const int n    = lane & 15;
    const int quad = lane >> 4;
    const int row0 = blockIdx.x * BM;

    // ---- stage + convert A (once) ----
#pragma unroll
    for (int i = 0; i < 4; ++i) {
        const int run  = t + 512 * i;           // (row, dcs, qs): 64*8*4 = 2048
        const int qs   = run & 3;
        const int dcs  = (run >> 2) & 7;
        const int row  = run >> 5;
        const float* src = z_e + (size_t)(row0 + row) * D_DIM + dcs * 32 + qs * 8;
        float x[8];
        *(float4*)(x)     = *(const float4*)(src);
        *(float4*)(x + 4) = *(const float4*)(src + 4);
        s16x8 hv, mv, lv;
#pragma unroll
        for (int j = 0; j < 8; ++j) {
            const float xx = x[j];
            const unsigned short bh = f2bf(xx);
            const float r1 = xx - bf2f(bh);
            const unsigned short bm = f2bf(r1);
            hv[j] = (short)bh; mv[j] = (short)bm; lv[j] = (short)f2bf(r1 - bf2f(bm));
        }
        const int rtile = row >> 4;
        const int ls    = qs * 16 + (row & 15);
        *(s16x8*)&As[((0 * 4 + rtile) * 8 + dcs) * 512 + ls * 8] = hv;
        *(s16x8*)&As[((1 * 4 + rtile) * 8 + dcs) * 512 + ls * 8] = mv;
        *(s16x8*)&As[((2 * 4 + rtile) * 8 + dcs) * 512 + ls * 8] = lv;
    }
    __syncthreads();

    float bv[16];
    int   bidx[16];
#pragma unroll
    for (int s = 0; s < 16; ++s) { bv[s] = 3.0e38f; bidx[s] = 0; }

    f32x4 acc[4][2];
#pragma unroll
    for (int rt = 0; rt < 4; ++rt)
#pragma unroll
        for (int u = 0; u < 2; ++u) acc[rt][u] = (f32x4){0.f, 0.f, 0.f, 0.f};

    float e2r[2];
    s16x8 b0[2][3], b1[2][3];
    load_b(escr, 0, 0, w, lane, b0);

    // 128 steps = (kt 0..15) x (dc 0..7); ping-pong prefetch distance 1.
    // b1's loads are younger than b0's -> waiting on b0 never drains b1 (vmcnt(N)).
#pragma unroll 1
    for (int it = 0; it < 64; ++it) {
        const int s0 = it * 2, s1 = s0 + 1, s2 = s1 + 1;
        load_b(escr, s1 >> 3, s1 & 7, w, lane, b1);
        proc_step(As, e2g, s0 >> 3, s0 & 7, w, lane, n, b0, acc, e2r, bv, bidx);
        if (it < 63) load_b(escr, s2 >> 3, s2 & 7, w, lane, b0);
        proc_step(As, e2g, s1 >> 3, s1 & 7, w, lane, n, b1, acc, e2r, bv, bidx);
    }

    // butterfly over 16 lanes (codes interleave mod 16 -> lex tie-break)
#pragma unroll
    for (int slot = 0; slot < 16; ++slot) {
#pragma unroll
        for (int mask = 1; mask < 16; mask <<= 1) {
            const float ov = __shfl_xor(bv[slot], mask);
            const int   oi = __shfl_xor(bidx[slot], mask);
            if (ov < bv[slot] || (ov == bv[slot] && oi < bidx[slot])) {
                bv[slot] = ov; bidx[slot] = oi;
            }
        }
    }
    if (n == 0) {
#pragma unroll
        for (int rt = 0; rt < 4; ++rt)
#pragma unroll
            for (int r = 0; r < 4; ++r) {
                const int row_local = rt * 16 + quad * 4 + r;   // C/D: row=quad*4+reg
                redv[row_local][w] = bv[rt * 4 + r];
                redi[row_local][w] = bidx[rt * 4 + r];
            }
    }
    __syncthreads();
    if (t < 64) {
        float v = redv[t][0];
        int  bi = redi[t][0];
#pragma unroll
        for (int j = 1; j < 8; ++j) {
            const float v2 = redv[t][j];
            const int   i2 = redi[t][j];
            if (v2 < v || (v2 == v && i2 < bi)) { v = v2; bi = i2; }
        }
        bk_lds[t] = bi;
        out[(size_t)N_TOK * D_DIM + (size_t)(row0 + t)] = (float)bi;
    }
    __syncthreads();

    // ---- fused output tail (nontemporal: bypass L2, keep B scratch hot) ----
    float* zq = out;
    float* oh = out + (size_t)N_TOK * D_DIM + N_TOK;

#pragma unroll 1
    for (int rr = 0; rr < 8; ++rr) {            // z_q: wave w owns rows w*8..w*8+7
        const int rl  = w * 8 + rr;
        const int row = row0 + rl;
        const int bk  = bk_lds[rl];
        f32x4 v = *(const f32x4*)&embed[(size_t)bk * D_DIM + lane * 4];
        __builtin_nontemporal_store(v, (f32x4*)&zq[(size_t)row * D_DIM + lane * 4]);
    }
    if (row0 < OH_SAFE_ROWS) {                  // one_hot (scratch-overlap rows deferred)
#pragma unroll 1
        for (int rr = 0; rr < 8; ++rr) {
            const int rl  = w * 8 + rr;
            const int row = row0 + rl;
            const int bk  = bk_lds[rl];
            float* ohrow = &oh[(size_t)row * K_CODE];
#pragma unroll
            for (int g = 0; g < 16; ++g) {
                const int base = (g * 64 + lane) * 4;
                f32x4 u;
                u.x = (bk == base    ) ? 1.0f : 0.0f;
                u.y = (bk == base + 1) ? 1.0f : 0.0f;
                u.z = (bk == base + 2) ? 1.0f : 0.0f;
                u.w = (bk == base + 3) ? 1.0f : 0.0f;
                __builtin_nontemporal_store(u, (f32x4*)&ohrow[base]);
            }
        }
    }
}

// ---------------------------------------------------------------------------
// Cleanup: one_hot for rows 32320..32767 (region overlapped the scratch).
// 28 blocks x 16 rows; runs after all argmin blocks (stream order).
// ---------------------------------------------------------------------------
__launch_bounds__(256, 8)
__global__ void vq_oh_tail(float* __restrict__ out) {
    __shared__ int bks[16];
    const int t    = threadIdx.x;
    const int w    = t >> 6;
    const int lane = t & 63;
    const int row0 = OH_SAFE_ROWS + blockIdx.x * 16;

    const float* idxf = out + (size_t)N_TOK * D_DIM;
    float* oh = out + (size_t)N_TOK * D_DIM + N_TOK;

    if (t < 16) bks[t] = (int)idxf[row0 + t];
    __syncthreads();

#pragma unroll 1
    for (int rr = 0; rr < 4; ++rr) {
        const int r   = rr * 4 + w;
        const int row = row0 + r;
        const int bk  = bks[r];
        float* ohrow = &oh[(size_t)row * K_CODE];
#pragma unroll
        for (int g = 0; g < 16; ++g) {
            const int base = (g * 64 + lane) * 4;
            f32x4 u;
            u.x = (bk == base    ) ? 1.0f : 0.0f;
            u.y = (bk == base + 1) ? 1.0f : 0.0f;
            u.z = (bk == base + 2) ? 1.0f : 0.0f;
            u.w = (bk == base + 3) ? 1.0f : 0.0f;
            __builtin_nontemporal_store(u, (f32x4*)&ohrow[base]);
        }
    }
}

extern "C" void kernel_launch(void* const* d_in, const int* in_sizes, int n_in,
                              void* d_out, int out_size, void* d_ws, size_t ws_size,
                              hipStream_t stream) {
    const float* z_e   = (const float*)d_in[0];
    const float* embed = (const float*)d_in[1];
    float* out = (float*)d_out;

    hipLaunchKernelGGL(vq_prep,        dim3(K_CODE / 8), dim3(256), 0, stream, embed, out);
    hipLaunchKernelGGL(vq_argmin_mfma, dim3(N_TOK / BM), dim3(512), 0, stream, z_e, embed, out);
    hipLaunchKernelGGL(vq_oh_tail,     dim3((N_TOK - OH_SAFE_ROWS) / 16), dim3(256), 0, stream, out);
}